// Round 6
// baseline (73.040 us; speedup 1.0000x reference)
//
#include <hip/hip_runtime.h>

// Problem constants (B,N,D,E) = (8,1024,128,8)
constexpr int B_ = 8, N_ = 1024, D_ = 128, E_ = 8;
constexpr int ROWS = B_ * N_;   // 8192 flattened (b,s) rows

typedef __attribute__((ext_vector_type(8))) _Float16 f16x8;  // 8 f16 (4 VGPRs)
typedef __attribute__((ext_vector_type(4))) float f32x4;     // MFMA accumulator

// ---------------------------------------------------------------------------
// Fully fused: per block (256 blocks x 512 thr = 8 waves), 32 rows.
// Phase 1: coef[32][8] -> LDS. Each wave streams 4 rows' edge slices
//          (32 float4/lane/row) + adj read inline (no LDS, consumed same
//          iteration, lane-pair broadcast).
// Phase 2: out[32][128] = sum_e coef_e * (x @ W[e]^T) via 16x16x32 f16 MFMA.
//          W[e] (64 KB f32) staged per-e from L2 -> cvt f16 -> swizzled LDS
//          (byte ^= (i&7)<<4); 8 waves = 2 row-tiles x 4 col-tile pairs,
//          2 accumulators/wave, 64 MFMA/wave total.
// W L2 re-read: 256 blocks x 512 KB = 128 MB (~4-6 us, tail).
// ---------------------------------------------------------------------------
__global__ __launch_bounds__(512)
void fused_kernel(const float* __restrict__ node,   // (ROWS, D)
                  const float* __restrict__ edge,   // (ROWS, N, E)
                  const float* __restrict__ adj,    // (ROWS, N)
                  const float* __restrict__ W,      // (E, D, D)
                  float* __restrict__ out)          // (ROWS, D)
{
    __shared__ _Float16 sW[D_ * D_];     // 32 KB, one e at a time, swizzled
    __shared__ float s_coef[32][E_];     // 1 KB

    const int tid  = threadIdx.x;
    const int wv   = tid >> 6;           // 0..7
    const int lane = tid & 63;
    const int rbase = blockIdx.x * 32;

    // ---------------- Phase 1: coef for rows rbase + wv*4 .. +3 ----------
    #pragma unroll 1
    for (int r = 0; r < 4; ++r) {
        const int row = rbase + wv * 4 + r;
        const float4* e4 = (const float4*)(edge + (size_t)row * (N_ * E_));
        const float*  ar = adj + (size_t)row * N_;
        float ax = 0.f, ay = 0.f, az = 0.f, aw = 0.f;
        #pragma unroll 8
        for (int i = 0; i < 32; ++i) {
            float4 ev = e4[i * 64 + lane];
            float a   = ar[i * 32 + (lane >> 1)];   // o = (i*64+lane)/2
            ax += a * ev.x; ay += a * ev.y; az += a * ev.z; aw += a * ev.w;
        }
        // reduce over lanes, preserving parity bit 0 (e-half = lane&1)
        #pragma unroll
        for (int m = 2; m <= 32; m <<= 1) {
            ax += __shfl_xor(ax, m, 64);
            ay += __shfl_xor(ay, m, 64);
            az += __shfl_xor(az, m, 64);
            aw += __shfl_xor(aw, m, 64);
        }
        if (lane < 2) {  // lane 0 -> e0..3, lane 1 -> e4..7
            float4 v; v.x = ax; v.y = ay; v.z = az; v.w = aw;
            *(float4*)&s_coef[wv * 4 + r][lane * 4] = v;
        }
    }

    // ---------------- Phase 2 setup ---------------------------------------
    const int l16 = lane & 15;
    const int lk  = lane >> 4;           // k-group 0..3
    const int rt  = wv >> 2;             // row-tile 0..1
    const int ct0 = wv & 3;              // col-tiles ct0, ct0+4
    const int myrow = rbase + rt * 16 + l16;

    // stage W[0]: thread -> 32 f16 (i = tid>>2, j = (tid&3)*32)
    const int si = tid >> 2;
    const int sj = (tid & 3) * 32;
    const int sxr = (si & 7) << 4;
    char* lp = (char*)sW;
    const int sbyte = (si * D_ + sj) * 2;
    {
        const float* gp = W + (size_t)si * D_ + sj;   // e = 0
        #pragma unroll
        for (int q = 0; q < 4; ++q) {
            float4 a = ((const float4*)gp)[q * 2];
            float4 b = ((const float4*)gp)[q * 2 + 1];
            f16x8 v;
            v[0] = (_Float16)a.x; v[1] = (_Float16)a.y;
            v[2] = (_Float16)a.z; v[3] = (_Float16)a.w;
            v[4] = (_Float16)b.x; v[5] = (_Float16)b.y;
            v[6] = (_Float16)b.z; v[7] = (_Float16)b.w;
            *(f16x8*)(lp + ((sbyte + q * 16) ^ sxr)) = v;
        }
    }
    __syncthreads();   // coef + sW[e=0] visible

    // per-lane coef row + x slices
    float cf[E_];
    {
        float4 c0 = *(const float4*)&s_coef[rt * 16 + l16][0];
        float4 c1 = *(const float4*)&s_coef[rt * 16 + l16][4];
        cf[0] = c0.x; cf[1] = c0.y; cf[2] = c0.z; cf[3] = c0.w;
        cf[4] = c1.x; cf[5] = c1.y; cf[6] = c1.z; cf[7] = c1.w;
    }
    const float* xrow = node + (size_t)myrow * D_;
    float xv[4][8];
    #pragma unroll
    for (int q = 0; q < 4; ++q) {
        const float4* p = (const float4*)(xrow + q * 32 + lk * 8);
        float4 a = p[0], b = p[1];
        xv[q][0] = a.x; xv[q][1] = a.y; xv[q][2] = a.z; xv[q][3] = a.w;
        xv[q][4] = b.x; xv[q][5] = b.y; xv[q][6] = b.z; xv[q][7] = b.w;
    }

    // ---------------- Phase 2 main loop ----------------------------------
    f32x4 acc0 = {}, acc1 = {};
    #pragma unroll 1
    for (int e = 0; e < E_; ++e) {
        const float cfe = cf[e];
        #pragma unroll
        for (int js = 0; js < 4; ++js) {
            f16x8 af;
            #pragma unroll
            for (int t = 0; t < 8; ++t) af[t] = (_Float16)(cfe * xv[js][t]);
            const int j = js * 32 + lk * 8;
            const int b0 = (((ct0 * 16 + l16) * D_ + j) * 2) ^ ((l16 & 7) << 4);
            const int b1 = ((((ct0 + 4) * 16 + l16) * D_ + j) * 2) ^ ((l16 & 7) << 4);
            f16x8 bf0 = *(const f16x8*)((const char*)sW + b0);
            f16x8 bf1 = *(const f16x8*)((const char*)sW + b1);
            acc0 = __builtin_amdgcn_mfma_f32_16x16x32_f16(af, bf0, acc0, 0, 0, 0);
            acc1 = __builtin_amdgcn_mfma_f32_16x16x32_f16(af, bf1, acc1, 0, 0, 0);
        }
        if (e < E_ - 1) {
            __syncthreads();   // all waves done reading sW[e]
            const float* gp = W + ((size_t)(e + 1) * D_ + si) * D_ + sj;
            #pragma unroll
            for (int q = 0; q < 4; ++q) {
                float4 a = ((const float4*)gp)[q * 2];
                float4 b = ((const float4*)gp)[q * 2 + 1];
                f16x8 v;
                v[0] = (_Float16)a.x; v[1] = (_Float16)a.y;
                v[2] = (_Float16)a.z; v[3] = (_Float16)a.w;
                v[4] = (_Float16)b.x; v[5] = (_Float16)b.y;
                v[6] = (_Float16)b.z; v[7] = (_Float16)b.w;
                *(f16x8*)(lp + ((sbyte + q * 16) ^ sxr)) = v;
            }
            __syncthreads();   // sW[e+1] ready
        }
    }

    // ---------------- Epilogue: C/D layout col=lane&15, row=(lane>>4)*4+reg
    const int col0 = ct0 * 16 + l16;
    #pragma unroll
    for (int t = 0; t < 4; ++t) {
        const size_t orow = (size_t)(rbase + rt * 16 + lk * 4 + t) * D_;
        out[orow + col0]      = acc0[t];
        out[orow + col0 + 64] = acc1[t];
    }
}

extern "C" void kernel_launch(void* const* d_in, const int* in_sizes, int n_in,
                              void* d_out, int out_size, void* d_ws, size_t ws_size,
                              hipStream_t stream) {
    (void)in_sizes; (void)n_in; (void)out_size; (void)d_ws; (void)ws_size;
    const float* node = (const float*)d_in[0];   // (8,1024,128)
    const float* edge = (const float*)d_in[1];   // (8,1024,1024,8)
    const float* adj  = (const float*)d_in[2];   // (8,1024,1024)
    const float* W    = (const float*)d_in[3];   // (8,128,128)

    fused_kernel<<<ROWS / 32, 512, 0, stream>>>(node, edge, adj, W, (float*)d_out);
}

// Round 8
// 62.099 us; speedup vs baseline: 1.1762x; 1.1762x over previous
//
#include <hip/hip_runtime.h>

// Problem constants (B,N,D,E) = (8,1024,128,8)
constexpr int B_ = 8, N_ = 1024, D_ = 128, E_ = 8;
constexpr int ROWS = B_ * N_;   // 8192 flattened (b,s) rows

typedef __attribute__((ext_vector_type(8))) _Float16 f16x8;  // 8 f16 (4 VGPRs)
typedef __attribute__((ext_vector_type(4))) _Float16 f16x4;
typedef __attribute__((ext_vector_type(4))) float f32x4;     // MFMA accumulator
typedef __attribute__((ext_vector_type(4))) float f32x4v;    // native vec for NT loads

// ---------------------------------------------------------------------------
// Kernel A (R4 structure + NT loads): fused coef + W->f16 prep.
//  blocks [0, 4096): coef for rows {2*blk, 2*blk+1}, one row per wave.
//    coef[row][e] = sum_o adj[row][o] * edge[row][o][e]
//    edge/adj are read-once streams -> non-temporal loads (no cache alloc).
//  blocks [4096, 4128): Wh[e][i][j] = f16(W[e][i][j])  (linear layout).
// ---------------------------------------------------------------------------
__global__ __launch_bounds__(128)
void coef_wprep_kernel(const float* __restrict__ edge,   // (ROWS, N, E)
                       const float* __restrict__ adj,    // (ROWS, N)
                       const float* __restrict__ W,      // (E, D, D)
                       float* __restrict__ coef,         // (ROWS, E)
                       _Float16* __restrict__ Wh)        // (E, D, D)
{
    const int blk = blockIdx.x;
    const int tid = threadIdx.x;

    if (blk >= ROWS / 2) {
        // --- wprep role: 32 blocks x 128 threads x 8 float4 = 32768 float4
        const int b = blk - ROWS / 2;
        #pragma unroll
        for (int q = 0; q < 8; ++q) {
            const int i = b * 1024 + q * 128 + tid;
            float4 v = ((const float4*)W)[i];
            f16x4 h;
            h[0] = (_Float16)v.x; h[1] = (_Float16)v.y;
            h[2] = (_Float16)v.z; h[3] = (_Float16)v.w;
            ((f16x4*)Wh)[i] = h;
        }
        return;
    }

    __shared__ float s_adj[2][N_];
    const int wv   = tid >> 6;
    const int lane = tid & 63;
    const int row  = blk * 2 + wv;

    // stage this wave's adj row: 256 float4 / 64 lanes = 4 each (NT: read-once)
    {
        const f32x4v* ap = (const f32x4v*)(adj + (size_t)row * N_);
        f32x4v* sp = (f32x4v*)s_adj[wv];
        #pragma unroll
        for (int q = 0; q < 4; ++q)
            sp[q * 64 + lane] = __builtin_nontemporal_load(&ap[q * 64 + lane]);
    }
    __syncthreads();

    // stream edge row (NT loads): float4 f covers o = f/2, e-half = f&1
    const f32x4v* e4 = (const f32x4v*)(edge + (size_t)row * N_ * E_);
    float ax = 0.f, ay = 0.f, az = 0.f, aw = 0.f;
    #pragma unroll 8
    for (int i = 0; i < 32; ++i) {
        f32x4v ev = __builtin_nontemporal_load(&e4[i * 64 + lane]);
        float a = s_adj[wv][(i * 64 + lane) >> 1];
        ax += a * ev.x; ay += a * ev.y; az += a * ev.z; aw += a * ev.w;
    }
    // reduce over lanes, preserving parity bit 0 (e-half)
    #pragma unroll
    for (int m = 2; m <= 32; m <<= 1) {
        ax += __shfl_xor(ax, m, 64);
        ay += __shfl_xor(ay, m, 64);
        az += __shfl_xor(az, m, 64);
        aw += __shfl_xor(aw, m, 64);
    }
    if (lane < 2) {   // lane 0 -> e0..3, lane 1 -> e4..7
        float4 r; r.x = ax; r.y = ay; r.z = az; r.w = aw;
        ((float4*)(coef + (size_t)row * E_))[lane] = r;
    }
}

// ---------------------------------------------------------------------------
// Kernel B (identical to R4): out = A @ Wf  (8192 x 128, K = 1024), f16 MFMA.
// Block = 512 thr = 8 waves; tile 128 rows x 16 cols. Grid = 64 rblk x 8 cblk.
// B-slice Wh[e][cbase+i16][j] (32 KB) reg-staged into LDS with XOR swizzle,
// reused by all 8 row-tiles. cblk = bid&7 aligns with XCD round-robin.
// ---------------------------------------------------------------------------
__global__ __launch_bounds__(512)
void gemm_kernel(const float* __restrict__ node,   // (ROWS, D)
                 const float* __restrict__ coef,   // (ROWS, E)
                 const _Float16* __restrict__ Wh,  // (E, D, D)
                 float* __restrict__ out)          // (ROWS, D)
{
    __shared__ _Float16 sW[E_ * 16 * D_];   // 32 KB, [e][i16][j], swizzled
    const int tid  = threadIdx.x;
    const int cblk = blockIdx.x & 7;
    const int rblk = blockIdx.x >> 3;
    const int cbase = cblk * 16;

    // --- stage B-slice: thread -> 32 consecutive f16 (4 x 16B), swizzled write
    {
        const int lin = tid * 32;                 // f16 index within slice
        const int e   = lin >> 11;
        const int rem = lin & 2047;
        const int i16 = rem >> 7;
        const int j   = rem & 127;
        const _Float16* gp = Wh + ((size_t)e * D_ + (cbase + i16)) * D_ + j;
        char* lp = (char*)sW;
        const int xr = (i16 & 7) << 4;
        #pragma unroll
        for (int q = 0; q < 4; ++q) {
            f16x8 v = *(const f16x8*)(gp + q * 8);
            *(f16x8*)(lp + ((lin * 2 + q * 16) ^ xr)) = v;
        }
    }

    const int wv   = tid >> 6;          // row-tile 0..7
    const int lane = tid & 63;
    const int l16  = lane & 15;
    const int lk   = lane >> 4;         // k-group 0..3
    const int rbase = rblk * 128 + wv * 16;
    const int r = rbase + l16;

    // hoisted coef row
    float cf[E_];
    {
        const float4* cp = (const float4*)(coef + (size_t)r * E_);
        float4 c0 = cp[0], c1 = cp[1];
        cf[0] = c0.x; cf[1] = c0.y; cf[2] = c0.z; cf[3] = c0.w;
        cf[4] = c1.x; cf[5] = c1.y; cf[6] = c1.z; cf[7] = c1.w;
    }
    // preload x slices: xv[q][t] = x[q*32 + lk*8 + t]
    const float* xrow = node + (size_t)r * D_;
    float xv[4][8];
    #pragma unroll
    for (int q = 0; q < 4; ++q) {
        const float4* p = (const float4*)(xrow + q * 32 + lk * 8);
        float4 a = p[0], b = p[1];
        xv[q][0] = a.x; xv[q][1] = a.y; xv[q][2] = a.z; xv[q][3] = a.w;
        xv[q][4] = b.x; xv[q][5] = b.y; xv[q][6] = b.z; xv[q][7] = b.w;
    }

    __syncthreads();   // sW ready

    f32x4 acc = {};
    const int xr = (l16 & 7) << 4;
    #pragma unroll
    for (int e = 0; e < E_; ++e) {
        const float cfe = cf[e];
        #pragma unroll
        for (int js = 0; js < 4; ++js) {
            f16x8 af;
            #pragma unroll
            for (int t = 0; t < 8; ++t) af[t] = (_Float16)(cfe * xv[js][t]);
            const int boff = (((e * 16 + l16) * D_ + js * 32 + lk * 8) * 2) ^ xr;
            f16x8 bf = *(const f16x8*)((const char*)sW + boff);
            acc = __builtin_amdgcn_mfma_f32_16x16x32_f16(af, bf, acc, 0, 0, 0);
        }
    }
    // C/D layout: col = lane&15, row = (lane>>4)*4 + reg
    const int col = cbase + l16;
    #pragma unroll
    for (int t = 0; t < 4; ++t) {
        out[(size_t)(rbase + lk * 4 + t) * D_ + col] = acc[t];
    }
}

extern "C" void kernel_launch(void* const* d_in, const int* in_sizes, int n_in,
                              void* d_out, int out_size, void* d_ws, size_t ws_size,
                              hipStream_t stream) {
    (void)in_sizes; (void)n_in; (void)out_size; (void)ws_size;
    const float* node = (const float*)d_in[0];   // (8,1024,128)
    const float* edge = (const float*)d_in[1];   // (8,1024,1024,8)
    const float* adj  = (const float*)d_in[2];   // (8,1024,1024)
    const float* W    = (const float*)d_in[3];   // (8,128,128)

    float*     coefp = (float*)d_ws;                        // 256 KB
    _Float16*  Wh    = (_Float16*)((char*)d_ws + 256*1024); // 256 KB

    coef_wprep_kernel<<<ROWS / 2 + 32, 128, 0, stream>>>(edge, adj, W, coefp, Wh);
    gemm_kernel<<<(ROWS / 128) * 8, 512, 0, stream>>>(node, coefp, Wh, (float*)d_out);
}

// Round 9
// 58.933 us; speedup vs baseline: 1.2394x; 1.0537x over previous
//
#include <hip/hip_runtime.h>

// Problem constants (B,N,D,E) = (8,1024,128,8)
constexpr int B_ = 8, N_ = 1024, D_ = 128, E_ = 8;
constexpr int ROWS = B_ * N_;   // 8192 flattened (b,s) rows

typedef __attribute__((ext_vector_type(8))) _Float16 f16x8;  // 8 f16 (4 VGPRs)
typedef __attribute__((ext_vector_type(4))) _Float16 f16x4;
typedef __attribute__((ext_vector_type(4))) float f32x4;     // MFMA accumulator

// ---------------------------------------------------------------------------
// Kernel A: fused coef + W->f16 prep.
//  blocks [0, 4096): coef for rows {2*blk, 2*blk+1}, one row per wave.
//    coef[row][e] = sum_o adj[row][o] * edge[row][o][e]
//    edge: 1 KB/wave/iter coalesced float4; adj read DIRECTLY from global
//    (lane pairs share an address -> 128 B coalesced segment/iter). No LDS,
//    no barrier — waves fully independent.
//  blocks [4096, 4128): Wh[e][i][j] = f16(W[e][i][j])  (linear layout).
// ---------------------------------------------------------------------------
__global__ __launch_bounds__(128)
void coef_wprep_kernel(const float* __restrict__ edge,   // (ROWS, N, E)
                       const float* __restrict__ adj,    // (ROWS, N)
                       const float* __restrict__ W,      // (E, D, D)
                       float* __restrict__ coef,         // (ROWS, E)
                       _Float16* __restrict__ Wh)        // (E, D, D)
{
    const int blk = blockIdx.x;
    const int tid = threadIdx.x;

    if (blk >= ROWS / 2) {
        // --- wprep role: 32 blocks x 128 threads x 8 float4 = 32768 float4
        const int b = blk - ROWS / 2;
        #pragma unroll
        for (int q = 0; q < 8; ++q) {
            const int i = b * 1024 + q * 128 + tid;
            float4 v = ((const float4*)W)[i];
            f16x4 h;
            h[0] = (_Float16)v.x; h[1] = (_Float16)v.y;
            h[2] = (_Float16)v.z; h[3] = (_Float16)v.w;
            ((f16x4*)Wh)[i] = h;
        }
        return;
    }

    const int wv   = tid >> 6;
    const int lane = tid & 63;
    const int row  = blk * 2 + wv;

    // stream edge row; adj inline: float4 f = i*64+lane covers o = f/2,
    // e-half = f&1 (= lane&1)
    const float4* e4 = (const float4*)(edge + (size_t)row * N_ * E_);
    const float*  ar = adj + (size_t)row * N_;
    float ax = 0.f, ay = 0.f, az = 0.f, aw = 0.f;
    #pragma unroll 8
    for (int i = 0; i < 32; ++i) {
        float4 ev = e4[i * 64 + lane];
        float a   = ar[i * 32 + (lane >> 1)];
        ax += a * ev.x; ay += a * ev.y; az += a * ev.z; aw += a * ev.w;
    }
    // reduce over lanes, preserving parity bit 0 (e-half)
    #pragma unroll
    for (int m = 2; m <= 32; m <<= 1) {
        ax += __shfl_xor(ax, m, 64);
        ay += __shfl_xor(ay, m, 64);
        az += __shfl_xor(az, m, 64);
        aw += __shfl_xor(aw, m, 64);
    }
    if (lane < 2) {   // lane 0 -> e0..3, lane 1 -> e4..7
        float4 r; r.x = ax; r.y = ay; r.z = az; r.w = aw;
        ((float4*)(coef + (size_t)row * E_))[lane] = r;
    }
}

// ---------------------------------------------------------------------------
// Kernel B (identical to R4): out = A @ Wf  (8192 x 128, K = 1024), f16 MFMA.
// Block = 512 thr = 8 waves; tile 128 rows x 16 cols. Grid = 64 rblk x 8 cblk.
// B-slice Wh[e][cbase+i16][j] (32 KB) reg-staged into LDS with XOR swizzle,
// reused by all 8 row-tiles. cblk = bid&7 aligns with XCD round-robin.
// ---------------------------------------------------------------------------
__global__ __launch_bounds__(512)
void gemm_kernel(const float* __restrict__ node,   // (ROWS, D)
                 const float* __restrict__ coef,   // (ROWS, E)
                 const _Float16* __restrict__ Wh,  // (E, D, D)
                 float* __restrict__ out)          // (ROWS, D)
{
    __shared__ _Float16 sW[E_ * 16 * D_];   // 32 KB, [e][i16][j], swizzled
    const int tid  = threadIdx.x;
    const int cblk = blockIdx.x & 7;
    const int rblk = blockIdx.x >> 3;
    const int cbase = cblk * 16;

    // --- stage B-slice: thread -> 32 consecutive f16 (4 x 16B), swizzled write
    {
        const int lin = tid * 32;                 // f16 index within slice
        const int e   = lin >> 11;
        const int rem = lin & 2047;
        const int i16 = rem >> 7;
        const int j   = rem & 127;
        const _Float16* gp = Wh + ((size_t)e * D_ + (cbase + i16)) * D_ + j;
        char* lp = (char*)sW;
        const int xr = (i16 & 7) << 4;
        #pragma unroll
        for (int q = 0; q < 4; ++q) {
            f16x8 v = *(const f16x8*)(gp + q * 8);
            *(f16x8*)(lp + ((lin * 2 + q * 16) ^ xr)) = v;
        }
    }

    const int wv   = tid >> 6;          // row-tile 0..7
    const int lane = tid & 63;
    const int l16  = lane & 15;
    const int lk   = lane >> 4;         // k-group 0..3
    const int rbase = rblk * 128 + wv * 16;
    const int r = rbase + l16;

    // hoisted coef row
    float cf[E_];
    {
        const float4* cp = (const float4*)(coef + (size_t)r * E_);
        float4 c0 = cp[0], c1 = cp[1];
        cf[0] = c0.x; cf[1] = c0.y; cf[2] = c0.z; cf[3] = c0.w;
        cf[4] = c1.x; cf[5] = c1.y; cf[6] = c1.z; cf[7] = c1.w;
    }
    // preload x slices: xv[q][t] = x[q*32 + lk*8 + t]
    const float* xrow = node + (size_t)r * D_;
    float xv[4][8];
    #pragma unroll
    for (int q = 0; q < 4; ++q) {
        const float4* p = (const float4*)(xrow + q * 32 + lk * 8);
        float4 a = p[0], b = p[1];
        xv[q][0] = a.x; xv[q][1] = a.y; xv[q][2] = a.z; xv[q][3] = a.w;
        xv[q][4] = b.x; xv[q][5] = b.y; xv[q][6] = b.z; xv[q][7] = b.w;
    }

    __syncthreads();   // sW ready

    f32x4 acc = {};
    const int xr = (l16 & 7) << 4;
    #pragma unroll
    for (int e = 0; e < E_; ++e) {
        const float cfe = cf[e];
        #pragma unroll
        for (int js = 0; js < 4; ++js) {
            f16x8 af;
            #pragma unroll
            for (int t = 0; t < 8; ++t) af[t] = (_Float16)(cfe * xv[js][t]);
            const int boff = (((e * 16 + l16) * D_ + js * 32 + lk * 8) * 2) ^ xr;
            f16x8 bf = *(const f16x8*)((const char*)sW + boff);
            acc = __builtin_amdgcn_mfma_f32_16x16x32_f16(af, bf, acc, 0, 0, 0);
        }
    }
    // C/D layout: col = lane&15, row = (lane>>4)*4 + reg
    const int col = cbase + l16;
    #pragma unroll
    for (int t = 0; t < 4; ++t) {
        out[(size_t)(rbase + lk * 4 + t) * D_ + col] = acc[t];
    }
}

extern "C" void kernel_launch(void* const* d_in, const int* in_sizes, int n_in,
                              void* d_out, int out_size, void* d_ws, size_t ws_size,
                              hipStream_t stream) {
    (void)in_sizes; (void)n_in; (void)out_size; (void)ws_size;
    const float* node = (const float*)d_in[0];   // (8,1024,128)
    const float* edge = (const float*)d_in[1];   // (8,1024,1024,8)
    const float* adj  = (const float*)d_in[2];   // (8,1024,1024)
    const float* W    = (const float*)d_in[3];   // (8,128,128)

    float*     coefp = (float*)d_ws;                        // 256 KB
    _Float16*  Wh    = (_Float16*)((char*)d_ws + 256*1024); // 256 KB

    coef_wprep_kernel<<<ROWS / 2 + 32, 128, 0, stream>>>(edge, adj, W, coefp, Wh);
    gemm_kernel<<<(ROWS / 128) * 8, 512, 0, stream>>>(node, coefp, Wh, (float*)d_out);
}